// Round 1
// baseline (529.527 us; speedup 1.0000x reference)
//
#include <hip/hip_runtime.h>
#include <math.h>

#define NR 8192
#define INF_ 512
#define OUTF 256
#define ALPHA 0.2f

// ---------------- Kernel 1: H = X @ W  (fp32 vector GEMM) ----------------
// BM=64, BN=64, BK=16, 256 threads, 4x4 micro-tile per thread.
__global__ __launch_bounds__(256) void k_gemm(const float* __restrict__ A,
                                              const float* __restrict__ W,
                                              float* __restrict__ H) {
    __shared__ float As[16][68];  // [k][m], row = 272B (16B-aligned)
    __shared__ float Bs[16][68];  // [k][n]
    const int tid = threadIdx.x;
    const int brow = blockIdx.x * 64;
    const int bcol = blockIdx.y * 64;
    const int tx = tid & 15, ty = tid >> 4;
    const int ar = tid >> 2;          // 0..63  (m within tile)
    const int ac = (tid & 3) << 2;    // 0,4,8,12 (k offset)
    const int br = tid >> 4;          // 0..15  (k row)
    const int bc = (tid & 15) << 2;   // 0..60  (n offset)

    float acc[4][4] = {};
    for (int k0 = 0; k0 < INF_; k0 += 16) {
        float4 av = *(const float4*)(A + (size_t)(brow + ar) * INF_ + k0 + ac);
        float4 bv = *(const float4*)(W + (size_t)(k0 + br) * OUTF + bcol + bc);
        __syncthreads();
        As[ac + 0][ar] = av.x; As[ac + 1][ar] = av.y;
        As[ac + 2][ar] = av.z; As[ac + 3][ar] = av.w;
        *(float4*)&Bs[br][bc] = bv;
        __syncthreads();
#pragma unroll
        for (int kk = 0; kk < 16; ++kk) {
            float4 a4 = *(const float4*)&As[kk][ty * 4];
            float4 b4 = *(const float4*)&Bs[kk][tx * 4];
            acc[0][0] = fmaf(a4.x, b4.x, acc[0][0]); acc[0][1] = fmaf(a4.x, b4.y, acc[0][1]);
            acc[0][2] = fmaf(a4.x, b4.z, acc[0][2]); acc[0][3] = fmaf(a4.x, b4.w, acc[0][3]);
            acc[1][0] = fmaf(a4.y, b4.x, acc[1][0]); acc[1][1] = fmaf(a4.y, b4.y, acc[1][1]);
            acc[1][2] = fmaf(a4.y, b4.z, acc[1][2]); acc[1][3] = fmaf(a4.y, b4.w, acc[1][3]);
            acc[2][0] = fmaf(a4.z, b4.x, acc[2][0]); acc[2][1] = fmaf(a4.z, b4.y, acc[2][1]);
            acc[2][2] = fmaf(a4.z, b4.z, acc[2][2]); acc[2][3] = fmaf(a4.z, b4.w, acc[2][3]);
            acc[3][0] = fmaf(a4.w, b4.x, acc[3][0]); acc[3][1] = fmaf(a4.w, b4.y, acc[3][1]);
            acc[3][2] = fmaf(a4.w, b4.z, acc[3][2]); acc[3][3] = fmaf(a4.w, b4.w, acc[3][3]);
        }
    }
#pragma unroll
    for (int m = 0; m < 4; ++m) {
        float4 o = make_float4(acc[m][0], acc[m][1], acc[m][2], acc[m][3]);
        *(float4*)(H + (size_t)(brow + ty * 4 + m) * OUTF + bcol + tx * 4) = o;
    }
}

// ---------------- Kernel 2: src = H @ a[:F], dst = H @ a[F:] ----------------
__global__ __launch_bounds__(256) void k_srcdst(const float* __restrict__ H,
                                                const float* __restrict__ a,
                                                float* __restrict__ src,
                                                float* __restrict__ dst) {
    const int wv = threadIdx.x >> 6;
    const int ln = threadIdx.x & 63;
    const int row = blockIdx.x * 4 + wv;
    float4 hv = *(const float4*)(H + (size_t)row * OUTF + ln * 4);
    float4 a1 = *(const float4*)(a + ln * 4);
    float4 a2 = *(const float4*)(a + OUTF + ln * 4);
    float s = hv.x * a1.x + hv.y * a1.y + hv.z * a1.z + hv.w * a1.w;
    float d = hv.x * a2.x + hv.y * a2.y + hv.z * a2.z + hv.w * a2.w;
#pragma unroll
    for (int o = 32; o > 0; o >>= 1) {
        s += __shfl_down(s, o);
        d += __shfl_down(d, o);
    }
    if (ln == 0) { src[row] = s; dst[row] = d; }
}

// ---------------- Kernel 3: sort dst (bitonic, LDS) + scalar scans ----------------
__global__ __launch_bounds__(1024) void k_sort(const float* __restrict__ dstv,
                                               float* __restrict__ dsts,
                                               int* __restrict__ perm,
                                               float* __restrict__ wplus,
                                               float* __restrict__ wminus,
                                               float* __restrict__ Splus,
                                               float* __restrict__ Sminus) {
    __shared__ float key[NR];
    __shared__ int idx[NR];
    const int tid = threadIdx.x;
    for (int e = tid; e < NR; e += 1024) { key[e] = dstv[e]; idx[e] = e; }
    __syncthreads();
    for (int len = 2; len <= NR; len <<= 1) {
        for (int str = len >> 1; str > 0; str >>= 1) {
            for (int e = tid; e < NR; e += 1024) {
                int p = e ^ str;
                if (p > e) {
                    float ke = key[e], kp = key[p];
                    bool up = ((e & len) == 0);
                    if ((ke > kp) == up) {
                        key[e] = kp; key[p] = ke;
                        int t = idx[e]; idx[e] = idx[p]; idx[p] = t;
                    }
                }
            }
            __syncthreads();
        }
    }
    const float D = key[NR - 1];
    for (int e = tid; e < NR; e += 1024) {
        float kv = key[e];
        dsts[e] = kv;
        perm[e] = idx[e];
        wplus[e] = expf(kv - D);
        wminus[e] = expf(ALPHA * kv);
    }
    __syncthreads();
    // scalar Hillis-Steele scans, ping-pong between key[] and idx[] (as float)
    float* bufA = key;
    float* bufB = (float*)idx;
    for (int e = tid; e < NR; e += 1024) bufA[e] = expf(key[e] - D);
    __syncthreads();
    float* pa = bufA; float* pb = bufB;
    for (int off = 1; off < NR; off <<= 1) {
        for (int e = tid; e < NR; e += 1024) {
            float v = pa[e];
            if (e >= off) v += pa[e - off];
            pb[e] = v;
        }
        __syncthreads();
        float* t = pa; pa = pb; pb = t;
    }
    for (int e = tid; e < NR; e += 1024) Splus[e + 1] = pa[e];
    if (tid == 0) Splus[0] = 0.f;
    __syncthreads();
    for (int e = tid; e < NR; e += 1024) pa[e] = wminus[e];
    __syncthreads();
    for (int off = 1; off < NR; off <<= 1) {
        for (int e = tid; e < NR; e += 1024) {
            float v = pa[e];
            if (e >= off) v += pa[e - off];
            pb[e] = v;
        }
        __syncthreads();
        float* t = pa; pa = pb; pb = t;
    }
    for (int e = tid; e < NR; e += 1024) Sminus[e + 1] = pa[e];
    if (tid == 0) Sminus[0] = 0.f;
}

// ---------------- Kernel 4: per-chunk (32-row) weighted sums ----------------
__global__ __launch_bounds__(256) void k_chunksum(const float* __restrict__ H,
                                                  const int* __restrict__ perm,
                                                  const float* __restrict__ wplus,
                                                  const float* __restrict__ wminus,
                                                  float* __restrict__ chunkP,
                                                  float* __restrict__ chunkM) {
    const int b = blockIdx.x, f = threadIdx.x;
    float aP = 0.f, aM = 0.f;
#pragma unroll 4
    for (int k = 0; k < 32; ++k) {
        int g = b * 32 + k;
        int p = perm[g];
        float hv = H[(size_t)p * OUTF + f];
        aP = fmaf(wplus[g], hv, aP);
        aM = fmaf(wminus[g], hv, aM);
    }
    chunkP[b * OUTF + f] = aP;
    chunkM[b * OUTF + f] = aM;
}

// ---------------- Kernel 5: scan chunk sums per column (wave scan) ----------------
__global__ __launch_bounds__(64) void k_chunkscan(const float* __restrict__ chunkP,
                                                  const float* __restrict__ chunkM,
                                                  float* __restrict__ offP,
                                                  float* __restrict__ offM,
                                                  float* __restrict__ PrefP,
                                                  float* __restrict__ PrefM) {
    const int f = blockIdx.x;
    const bool minus = (blockIdx.y != 0);
    const float* sv = minus ? chunkM : chunkP;
    float* dv = minus ? offM : offP;
    float* tot = minus ? PrefM : PrefP;
    const int l = threadIdx.x;
    float v0 = sv[(4 * l + 0) * OUTF + f];
    float v1 = sv[(4 * l + 1) * OUTF + f];
    float v2 = sv[(4 * l + 2) * OUTF + f];
    float v3 = sv[(4 * l + 3) * OUTF + f];
    float s = v0 + v1 + v2 + v3;
    float incl = s;
#pragma unroll
    for (int o = 1; o < 64; o <<= 1) {
        float t = __shfl_up(incl, o);
        if (l >= o) incl += t;
    }
    float excl = incl - s;
    dv[(4 * l + 0) * OUTF + f] = excl;
    dv[(4 * l + 1) * OUTF + f] = excl + v0;
    dv[(4 * l + 2) * OUTF + f] = excl + v0 + v1;
    dv[(4 * l + 3) * OUTF + f] = excl + v0 + v1 + v2;
    if (l == 63) tot[(size_t)NR * OUTF + f] = incl;  // grand total at index [8192]
}

// ---------------- Kernel 6: write full [8193][256] prefix arrays ----------------
__global__ __launch_bounds__(256) void k_writepref(const float* __restrict__ H,
                                                   const int* __restrict__ perm,
                                                   const float* __restrict__ wplus,
                                                   const float* __restrict__ wminus,
                                                   const float* __restrict__ offP,
                                                   const float* __restrict__ offM,
                                                   float* __restrict__ PrefP,
                                                   float* __restrict__ PrefM) {
    const int b = blockIdx.x, f = threadIdx.x;
    float aP = offP[b * OUTF + f];
    float aM = offM[b * OUTF + f];
    for (int k = 0; k < 32; ++k) {
        int g = b * 32 + k;
        PrefP[(size_t)g * OUTF + f] = aP;
        PrefM[(size_t)g * OUTF + f] = aM;
        int p = perm[g];
        float hv = H[(size_t)p * OUTF + f];
        aP = fmaf(wplus[g], hv, aP);
        aM = fmaf(wminus[g], hv, aM);
    }
}

// ---------------- Kernel 7: per-row combine + ELU ----------------
__global__ __launch_bounds__(256) void k_out(const float* __restrict__ src,
                                             const float* __restrict__ dsts,
                                             const float* __restrict__ Splus,
                                             const float* __restrict__ Sminus,
                                             const float* __restrict__ PrefP,
                                             const float* __restrict__ PrefM,
                                             float* __restrict__ out) {
    const int i = blockIdx.x, f = threadIdx.x;
    const float si = src[i];
    const float D = dsts[NR - 1];
    const float thr = -si;
    int lo = 0, hi = NR;
    while (lo < hi) {
        int mid = (lo + hi) >> 1;
        if (dsts[mid] <= thr) lo = mid + 1; else hi = mid;
    }
    const int t = lo;  // first index with dst > thr (positive branch = suffix [t, N))
    const float cP = expf(si + D);
    const float cM = expf(ALPHA * si);
    const float SP = Splus[NR] - Splus[t];
    const float SM = Sminus[t];
    const float inv = 1.f / (cP * SP + cM * SM);
    const float pP = PrefP[(size_t)NR * OUTF + f] - PrefP[(size_t)t * OUTF + f];
    const float pM = PrefM[(size_t)t * OUTF + f];
    const float v = (cP * pP + cM * pM) * inv;
    out[(size_t)i * OUTF + f] = v > 0.f ? v : expm1f(v);
}

extern "C" void kernel_launch(void* const* d_in, const int* in_sizes, int n_in,
                              void* d_out, int out_size, void* d_ws, size_t ws_size,
                              hipStream_t stream) {
    const float* X = (const float*)d_in[0];
    // d_in[1] = adj (unused by reference forward)
    const float* W = (const float*)d_in[2];
    const float* a = (const float*)d_in[3];
    float* out = (float*)d_out;

    char* ws = (char*)d_ws;
    size_t off = 0;
    auto carve = [&](size_t bytes) -> void* {
        void* p = ws + off;
        off += (bytes + 1023) & ~(size_t)1023;
        return p;
    };
    float* H      = (float*)carve((size_t)NR * OUTF * 4);
    float* src    = (float*)carve(NR * 4);
    float* dstv   = (float*)carve(NR * 4);
    float* dsts   = (float*)carve(NR * 4);
    int*   perm   = (int*)carve(NR * 4);
    float* wplus  = (float*)carve(NR * 4);
    float* wminus = (float*)carve(NR * 4);
    float* Splus  = (float*)carve((NR + 1) * 4);
    float* Sminus = (float*)carve((NR + 1) * 4);
    float* chunkP = (float*)carve(256 * OUTF * 4);
    float* chunkM = (float*)carve(256 * OUTF * 4);
    float* offP   = (float*)carve(256 * OUTF * 4);
    float* offM   = (float*)carve(256 * OUTF * 4);
    float* PrefP  = (float*)carve((size_t)(NR + 1) * OUTF * 4);
    float* PrefM  = (float*)carve((size_t)(NR + 1) * OUTF * 4);

    k_gemm<<<dim3(NR / 64, OUTF / 64), 256, 0, stream>>>(X, W, H);
    k_srcdst<<<NR / 4, 256, 0, stream>>>(H, a, src, dstv);
    k_sort<<<1, 1024, 0, stream>>>(dstv, dsts, perm, wplus, wminus, Splus, Sminus);
    k_chunksum<<<256, 256, 0, stream>>>(H, perm, wplus, wminus, chunkP, chunkM);
    k_chunkscan<<<dim3(OUTF, 2), 64, 0, stream>>>(chunkP, chunkM, offP, offM, PrefP, PrefM);
    k_writepref<<<256, 256, 0, stream>>>(H, perm, wplus, wminus, offP, offM, PrefP, PrefM);
    k_out<<<NR, 256, 0, stream>>>(src, dsts, Splus, Sminus, PrefP, PrefM, out);
}

// Round 3
// 444.417 us; speedup vs baseline: 1.1915x; 1.1915x over previous
//
#include <hip/hip_runtime.h>
#include <math.h>

#define NR 8192
#define INF_ 512
#define OUTF 256
#define ALPHA 0.2f

// ---------------- Kernel 1: H = X @ W  (fp32 vector GEMM) ----------------
// BM=64, BN=64, BK=16, 256 threads, 4x4 micro-tile per thread.
__global__ __launch_bounds__(256) void k_gemm(const float* __restrict__ A,
                                              const float* __restrict__ W,
                                              float* __restrict__ H) {
    __shared__ float As[16][68];  // [k][m]
    __shared__ float Bs[16][68];  // [k][n]
    const int tid = threadIdx.x;
    const int brow = blockIdx.x * 64;
    const int bcol = blockIdx.y * 64;
    const int tx = tid & 15, ty = tid >> 4;
    const int ar = tid >> 2;          // 0..63  (m within tile)
    const int ac = (tid & 3) << 2;    // 0,4,8,12 (k offset)
    const int br = tid >> 4;          // 0..15  (k row)
    const int bc = (tid & 15) << 2;   // 0..60  (n offset)

    float acc[4][4] = {};
    for (int k0 = 0; k0 < INF_; k0 += 16) {
        float4 av = *(const float4*)(A + (size_t)(brow + ar) * INF_ + k0 + ac);
        float4 bv = *(const float4*)(W + (size_t)(k0 + br) * OUTF + bcol + bc);
        __syncthreads();
        As[ac + 0][ar] = av.x; As[ac + 1][ar] = av.y;
        As[ac + 2][ar] = av.z; As[ac + 3][ar] = av.w;
        *(float4*)&Bs[br][bc] = bv;
        __syncthreads();
#pragma unroll
        for (int kk = 0; kk < 16; ++kk) {
            float4 a4 = *(const float4*)&As[kk][ty * 4];
            float4 b4 = *(const float4*)&Bs[kk][tx * 4];
            acc[0][0] = fmaf(a4.x, b4.x, acc[0][0]); acc[0][1] = fmaf(a4.x, b4.y, acc[0][1]);
            acc[0][2] = fmaf(a4.x, b4.z, acc[0][2]); acc[0][3] = fmaf(a4.x, b4.w, acc[0][3]);
            acc[1][0] = fmaf(a4.y, b4.x, acc[1][0]); acc[1][1] = fmaf(a4.y, b4.y, acc[1][1]);
            acc[1][2] = fmaf(a4.y, b4.z, acc[1][2]); acc[1][3] = fmaf(a4.y, b4.w, acc[1][3]);
            acc[2][0] = fmaf(a4.z, b4.x, acc[2][0]); acc[2][1] = fmaf(a4.z, b4.y, acc[2][1]);
            acc[2][2] = fmaf(a4.z, b4.z, acc[2][2]); acc[2][3] = fmaf(a4.z, b4.w, acc[2][3]);
            acc[3][0] = fmaf(a4.w, b4.x, acc[3][0]); acc[3][1] = fmaf(a4.w, b4.y, acc[3][1]);
            acc[3][2] = fmaf(a4.w, b4.z, acc[3][2]); acc[3][3] = fmaf(a4.w, b4.w, acc[3][3]);
        }
    }
#pragma unroll
    for (int m = 0; m < 4; ++m) {
        float4 o = make_float4(acc[m][0], acc[m][1], acc[m][2], acc[m][3]);
        *(float4*)(H + (size_t)(brow + ty * 4 + m) * OUTF + bcol + tx * 4) = o;
    }
}

// ---------------- Kernel 2: src = H @ a[:F], dst = H @ a[F:] ----------------
__global__ __launch_bounds__(256) void k_srcdst(const float* __restrict__ H,
                                                const float* __restrict__ a,
                                                float* __restrict__ src,
                                                float* __restrict__ dst) {
    const int wv = threadIdx.x >> 6;
    const int ln = threadIdx.x & 63;
    const int row = blockIdx.x * 4 + wv;
    float4 hv = *(const float4*)(H + (size_t)row * OUTF + ln * 4);
    float4 a1 = *(const float4*)(a + ln * 4);
    float4 a2 = *(const float4*)(a + OUTF + ln * 4);
    float s = hv.x * a1.x + hv.y * a1.y + hv.z * a1.z + hv.w * a1.w;
    float d = hv.x * a2.x + hv.y * a2.y + hv.z * a2.z + hv.w * a2.w;
#pragma unroll
    for (int o = 32; o > 0; o >>= 1) {
        s += __shfl_down(s, o);
        d += __shfl_down(d, o);
    }
    if (ln == 0) { src[row] = s; dst[row] = d; }
}

// ---------------- Kernel 3: rank-by-counting "sort" ----------------
// 256 blocks x 256 threads. Each block handles 32 elements, 8 scanner-lanes
// per element; scanner `sub` scans LDS slice [sub*1024, sub*1024+1024) with a
// +4*sub word stagger so the 8 distinct wave addresses hit disjoint bank quads.
__global__ __launch_bounds__(256) void k_rank(const float* __restrict__ dstv,
                                              float* __restrict__ dsts,
                                              int* __restrict__ perm) {
    __shared__ float key[NR];
    const int tid = threadIdx.x;
#pragma unroll
    for (int i = 0; i < 8; ++i)
        *(float4*)(key + 4 * (tid + 256 * i)) = *(const float4*)(dstv + 4 * (tid + 256 * i));
    __syncthreads();
    const int el = blockIdx.x * 32 + (tid >> 3);
    const int sub = tid & 7;
    const float my = key[el];
    const int sbase = sub << 10;
    int cnt = 0;
#pragma unroll 4
    for (int i = 0; i < 256; ++i) {
        const int off = ((i + sub) << 2) & 1023;
        const int k0 = sbase + off;
        float4 v = *(const float4*)(key + k0);
        cnt += (int)((v.x < my) | ((v.x == my) & (k0 + 0 < el)));
        cnt += (int)((v.y < my) | ((v.y == my) & (k0 + 1 < el)));
        cnt += (int)((v.z < my) | ((v.z == my) & (k0 + 2 < el)));
        cnt += (int)((v.w < my) | ((v.w == my) & (k0 + 3 < el)));
    }
    cnt += __shfl_down(cnt, 4);
    cnt += __shfl_down(cnt, 2);
    cnt += __shfl_down(cnt, 1);
    if (sub == 0) {
        dsts[cnt] = my;
        perm[cnt] = el;
    }
}

// ---------------- Kernel 4: weights + scalar prefix scans (1 block) ----------------
__global__ __launch_bounds__(1024) void k_scan(const float* __restrict__ dsts,
                                               float* __restrict__ wplus,
                                               float* __restrict__ wminus,
                                               float* __restrict__ Splus,
                                               float* __restrict__ Sminus) {
    __shared__ float wsP[16], wsM[16];
    const int t = threadIdx.x;
    const int lane = t & 63;
    const float D = dsts[NR - 1];
    float4 v0 = *(const float4*)(dsts + t * 8);
    float4 v1 = *(const float4*)(dsts + t * 8 + 4);
    float vv[8] = {v0.x, v0.y, v0.z, v0.w, v1.x, v1.y, v1.z, v1.w};
    float wp[8], wm[8];
    float sp = 0.f, sm = 0.f;
#pragma unroll
    for (int j = 0; j < 8; ++j) {
        wp[j] = expf(vv[j] - D);
        wm[j] = expf(ALPHA * vv[j]);
        sp += wp[j]; sm += wm[j];
    }
    *(float4*)(wplus + t * 8)      = make_float4(wp[0], wp[1], wp[2], wp[3]);
    *(float4*)(wplus + t * 8 + 4)  = make_float4(wp[4], wp[5], wp[6], wp[7]);
    *(float4*)(wminus + t * 8)     = make_float4(wm[0], wm[1], wm[2], wm[3]);
    *(float4*)(wminus + t * 8 + 4) = make_float4(wm[4], wm[5], wm[6], wm[7]);
    // wave-level inclusive scan of (sp, sm)
    float ip = sp, im = sm;
#pragma unroll
    for (int o = 1; o < 64; o <<= 1) {
        float tp = __shfl_up(ip, o);
        float tm = __shfl_up(im, o);
        if (lane >= o) { ip += tp; im += tm; }
    }
    if (lane == 63) { wsP[t >> 6] = ip; wsM[t >> 6] = im; }
    __syncthreads();
    if (t < 16) {
        float a = wsP[t], b = wsM[t];
#pragma unroll
        for (int o = 1; o < 16; o <<= 1) {
            float ta = __shfl_up(a, o);
            float tb = __shfl_up(b, o);
            if (t >= o) { a += ta; b += tb; }
        }
        wsP[t] = a; wsM[t] = b;  // inclusive wave sums
    }
    __syncthreads();
    const int w = t >> 6;
    float rp = (w ? wsP[w - 1] : 0.f) + (ip - sp);
    float rm = (w ? wsM[w - 1] : 0.f) + (im - sm);
#pragma unroll
    for (int j = 0; j < 8; ++j) {
        rp += wp[j]; rm += wm[j];
        Splus[t * 8 + j + 1] = rp;
        Sminus[t * 8 + j + 1] = rm;
    }
    if (t == 0) { Splus[0] = 0.f; Sminus[0] = 0.f; }
}

// ---------------- Kernel 5: per-chunk (32-row) weighted sums ----------------
__global__ __launch_bounds__(256) void k_chunksum(const float* __restrict__ H,
                                                  const int* __restrict__ perm,
                                                  const float* __restrict__ wplus,
                                                  const float* __restrict__ wminus,
                                                  float* __restrict__ chunkP,
                                                  float* __restrict__ chunkM) {
    const int b = blockIdx.x, f = threadIdx.x;
    float aP = 0.f, aM = 0.f;
#pragma unroll 4
    for (int k = 0; k < 32; ++k) {
        int g = b * 32 + k;
        int p = perm[g];
        float hv = H[(size_t)p * OUTF + f];
        aP = fmaf(wplus[g], hv, aP);
        aM = fmaf(wminus[g], hv, aM);
    }
    chunkP[b * OUTF + f] = aP;
    chunkM[b * OUTF + f] = aM;
}

// ---------------- Kernel 6: scan chunk sums per column (wave scan) ----------------
__global__ __launch_bounds__(64) void k_chunkscan(const float* __restrict__ chunkP,
                                                  const float* __restrict__ chunkM,
                                                  float* __restrict__ offP,
                                                  float* __restrict__ offM,
                                                  float* __restrict__ PrefP,
                                                  float* __restrict__ PrefM) {
    const int f = blockIdx.x;
    const bool minus = (blockIdx.y != 0);
    const float* sv = minus ? chunkM : chunkP;
    float* dv = minus ? offM : offP;
    float* tot = minus ? PrefM : PrefP;
    const int l = threadIdx.x;
    float v0 = sv[(4 * l + 0) * OUTF + f];
    float v1 = sv[(4 * l + 1) * OUTF + f];
    float v2 = sv[(4 * l + 2) * OUTF + f];
    float v3 = sv[(4 * l + 3) * OUTF + f];
    float s = v0 + v1 + v2 + v3;
    float incl = s;
#pragma unroll
    for (int o = 1; o < 64; o <<= 1) {
        float t = __shfl_up(incl, o);
        if (l >= o) incl += t;
    }
    float excl = incl - s;
    dv[(4 * l + 0) * OUTF + f] = excl;
    dv[(4 * l + 1) * OUTF + f] = excl + v0;
    dv[(4 * l + 2) * OUTF + f] = excl + v0 + v1;
    dv[(4 * l + 3) * OUTF + f] = excl + v0 + v1 + v2;
    if (l == 63) tot[(size_t)NR * OUTF + f] = incl;  // grand total row [8192]
}

// ---------------- Kernel 7: write full [8193][256] prefix arrays ----------------
__global__ __launch_bounds__(256) void k_writepref(const float* __restrict__ H,
                                                   const int* __restrict__ perm,
                                                   const float* __restrict__ wplus,
                                                   const float* __restrict__ wminus,
                                                   const float* __restrict__ offP,
                                                   const float* __restrict__ offM,
                                                   float* __restrict__ PrefP,
                                                   float* __restrict__ PrefM) {
    const int b = blockIdx.x, f = threadIdx.x;
    float aP = offP[b * OUTF + f];
    float aM = offM[b * OUTF + f];
    for (int k = 0; k < 32; ++k) {
        int g = b * 32 + k;
        PrefP[(size_t)g * OUTF + f] = aP;
        PrefM[(size_t)g * OUTF + f] = aM;
        int p = perm[g];
        float hv = H[(size_t)p * OUTF + f];
        aP = fmaf(wplus[g], hv, aP);
        aM = fmaf(wminus[g], hv, aM);
    }
}

// ---------------- Kernel 8: per-row combine + ELU ----------------
__global__ __launch_bounds__(256) void k_out(const float* __restrict__ src,
                                             const float* __restrict__ dsts,
                                             const float* __restrict__ Splus,
                                             const float* __restrict__ Sminus,
                                             const float* __restrict__ PrefP,
                                             const float* __restrict__ PrefM,
                                             float* __restrict__ out) {
    const int i = blockIdx.x, f = threadIdx.x;
    const float si = src[i];
    const float D = dsts[NR - 1];
    const float thr = -si;
    int lo = 0, hi = NR;
    while (lo < hi) {
        int mid = (lo + hi) >> 1;
        if (dsts[mid] <= thr) lo = mid + 1; else hi = mid;
    }
    const int t = lo;  // first index with dst > thr (positive branch = suffix [t, N))
    const float cP = expf(si + D);
    const float cM = expf(ALPHA * si);
    const float SP = Splus[NR] - Splus[t];
    const float SM = Sminus[t];
    const float inv = 1.f / (cP * SP + cM * SM);
    const float pP = PrefP[(size_t)NR * OUTF + f] - PrefP[(size_t)t * OUTF + f];
    const float pM = PrefM[(size_t)t * OUTF + f];
    const float v = (cP * pP + cM * pM) * inv;
    out[(size_t)i * OUTF + f] = v > 0.f ? v : expm1f(v);
}

extern "C" void kernel_launch(void* const* d_in, const int* in_sizes, int n_in,
                              void* d_out, int out_size, void* d_ws, size_t ws_size,
                              hipStream_t stream) {
    const float* X = (const float*)d_in[0];
    // d_in[1] = adj (unused by reference forward)
    const float* W = (const float*)d_in[2];
    const float* a = (const float*)d_in[3];
    float* out = (float*)d_out;

    char* ws = (char*)d_ws;
    size_t off = 0;
    auto carve = [&](size_t bytes) -> void* {
        void* p = ws + off;
        off += (bytes + 1023) & ~(size_t)1023;
        return p;
    };
    float* H      = (float*)carve((size_t)NR * OUTF * 4);
    float* src    = (float*)carve(NR * 4);
    float* dstv   = (float*)carve(NR * 4);
    float* dsts   = (float*)carve(NR * 4);
    int*   perm   = (int*)carve(NR * 4);
    float* wplus  = (float*)carve(NR * 4);
    float* wminus = (float*)carve(NR * 4);
    float* Splus  = (float*)carve((NR + 1) * 4);
    float* Sminus = (float*)carve((NR + 1) * 4);
    float* chunkP = (float*)carve(256 * OUTF * 4);
    float* chunkM = (float*)carve(256 * OUTF * 4);
    float* offP   = (float*)carve(256 * OUTF * 4);
    float* offM   = (float*)carve(256 * OUTF * 4);
    float* PrefP  = (float*)carve((size_t)(NR + 1) * OUTF * 4);
    float* PrefM  = (float*)carve((size_t)(NR + 1) * OUTF * 4);

    k_gemm<<<dim3(NR / 64, OUTF / 64), 256, 0, stream>>>(X, W, H);
    k_srcdst<<<NR / 4, 256, 0, stream>>>(H, a, src, dstv);
    k_rank<<<NR / 32, 256, 0, stream>>>(dstv, dsts, perm);
    k_scan<<<1, 1024, 0, stream>>>(dsts, wplus, wminus, Splus, Sminus);
    k_chunksum<<<256, 256, 0, stream>>>(H, perm, wplus, wminus, chunkP, chunkM);
    k_chunkscan<<<dim3(OUTF, 2), 64, 0, stream>>>(chunkP, chunkM, offP, offM, PrefP, PrefM);
    k_writepref<<<256, 256, 0, stream>>>(H, perm, wplus, wminus, offP, offM, PrefP, PrefM);
    k_out<<<NR, 256, 0, stream>>>(src, dsts, Splus, Sminus, PrefP, PrefM, out);
}

// Round 9
// 435.557 us; speedup vs baseline: 1.2157x; 1.0203x over previous
//
#include <hip/hip_runtime.h>
#include <math.h>

#define NR 8192
#define INF_ 512
#define OUTF 256
#define ALPHA 0.2f

typedef __attribute__((ext_vector_type(8))) short bf16x8;   // 8 bf16 = 4 VGPR
typedef __attribute__((ext_vector_type(4))) float f32x4;    // MFMA accumulator

#define MFMA(a, b, c) __builtin_amdgcn_mfma_f32_16x16x32_bf16((a), (b), (c), 0, 0, 0)

__device__ __forceinline__ ushort f2bf(float x) {  // RNE fp32->bf16
    unsigned u = __float_as_uint(x);
    unsigned r = (u + 0x7fff + ((u >> 16) & 1)) >> 16;
    return (ushort)r;
}
__device__ __forceinline__ float bf2f(ushort b) { return __uint_as_float((unsigned)b << 16); }

// ---------------- Kernel 0a: X -> Xhi, Xlo (bf16 split) ----------------
__global__ __launch_bounds__(256) void k_convX(const float* __restrict__ X,
                                               ushort* __restrict__ Xhi,
                                               ushort* __restrict__ Xlo) {
    const size_t i = ((size_t)blockIdx.x * 256 + threadIdx.x) * 8;
    float4 v0 = *(const float4*)(X + i);
    float4 v1 = *(const float4*)(X + i + 4);
    float f[8] = {v0.x, v0.y, v0.z, v0.w, v1.x, v1.y, v1.z, v1.w};
    ushort hi[8], lo[8];
#pragma unroll
    for (int j = 0; j < 8; ++j) {
        hi[j] = f2bf(f[j]);
        lo[j] = f2bf(f[j] - bf2f(hi[j]));
    }
    *(uint4*)(Xhi + i) = *(uint4*)hi;
    *(uint4*)(Xlo + i) = *(uint4*)lo;
}

// ---------------- Kernel 0b: W -> W^T hi/lo ([256 cols][512 k]) ----------------
__global__ __launch_bounds__(128) void k_convWT(const float* __restrict__ W,
                                                ushort* __restrict__ Wthi,
                                                ushort* __restrict__ Wtlo) {
    const int c = blockIdx.x;       // 0..255
    const int t = threadIdx.x;      // 0..127, k = 4t..4t+3
    ushort h[4], l[4];
#pragma unroll
    for (int j = 0; j < 4; ++j) {
        float x = W[(size_t)(4 * t + j) * OUTF + c];
        h[j] = f2bf(x);
        l[j] = f2bf(x - bf2f(h[j]));
    }
    *(ushort4*)(Wthi + (size_t)c * INF_ + 4 * t) = *(ushort4*)h;
    *(ushort4*)(Wtlo + (size_t)c * INF_ + 4 * t) = *(ushort4*)l;
}

// ---------------- Kernel 1: H = X @ W  (split-bf16 MFMA) ----------------
// 64x64 tile, 4 waves (16 rows each), BK=32, reg-staged single LDS buffer.
// LDS layout [kg4][idx64][8bf16] (kg stride = 512 ushorts): fragment reads are
// quarter-wave-contiguous 256B ds_read_b128 (conflict-free; 2-way is free).
__global__ __launch_bounds__(256) void k_gemm(const ushort* __restrict__ Xhi,
                                              const ushort* __restrict__ Xlo,
                                              const ushort* __restrict__ Wthi,
                                              const ushort* __restrict__ Wtlo,
                                              float* __restrict__ H) {
    __shared__ ushort sAhi[2048], sAlo[2048], sBhi[2048], sBlo[2048];
    const int tid = threadIdx.x;
    const int brow = blockIdx.x * 64;
    const int bcol = blockIdx.y * 64;
    const int lane = tid & 63;
    const int wr = tid >> 6;                 // wave id -> rows wr*16..+15
    const int s_kg = tid >> 6, s_i = tid & 63;
    const ushort* gAhi = Xhi + (size_t)(brow + s_i) * INF_ + s_kg * 8;
    const ushort* gAlo = Xlo + (size_t)(brow + s_i) * INF_ + s_kg * 8;
    const ushort* gBhi = Wthi + (size_t)(bcol + s_i) * INF_ + s_kg * 8;
    const ushort* gBlo = Wtlo + (size_t)(bcol + s_i) * INF_ + s_kg * 8;
    const int sw = tid * 8;                  // staging write slot (ushorts)

    const int fr = lane & 15, kg = lane >> 4;
    const int aoff = kg * 512 + (wr * 16 + fr) * 8;
    const int boff = kg * 512 + fr * 8;      // + nf*128 per 16-col group

    f32x4 acc0 = {0.f, 0.f, 0.f, 0.f};
    f32x4 acc1 = {0.f, 0.f, 0.f, 0.f};
    f32x4 acc2 = {0.f, 0.f, 0.f, 0.f};
    f32x4 acc3 = {0.f, 0.f, 0.f, 0.f};

    uint4 rAh = *(const uint4*)gAhi;
    uint4 rAl = *(const uint4*)gAlo;
    uint4 rBh = *(const uint4*)gBhi;
    uint4 rBl = *(const uint4*)gBlo;

    for (int t = 0; t < INF_ / 32; ++t) {
        *(uint4*)&sAhi[sw] = rAh;
        *(uint4*)&sAlo[sw] = rAl;
        *(uint4*)&sBhi[sw] = rBh;
        *(uint4*)&sBlo[sw] = rBl;
        __syncthreads();
        if (t < INF_ / 32 - 1) {             // prefetch next K-tile into regs
            rAh = *(const uint4*)(gAhi + (t + 1) * 32);
            rAl = *(const uint4*)(gAlo + (t + 1) * 32);
            rBh = *(const uint4*)(gBhi + (t + 1) * 32);
            rBl = *(const uint4*)(gBlo + (t + 1) * 32);
        }
        bf16x8 ahi = *(const bf16x8*)&sAhi[aoff];
        bf16x8 alo = *(const bf16x8*)&sAlo[aoff];
        bf16x8 bh0 = *(const bf16x8*)&sBhi[boff];
        bf16x8 bl0 = *(const bf16x8*)&sBlo[boff];
        bf16x8 bh1 = *(const bf16x8*)&sBhi[boff + 128];
        bf16x8 bl1 = *(const bf16x8*)&sBlo[boff + 128];
        bf16x8 bh2 = *(const bf16x8*)&sBhi[boff + 256];
        bf16x8 bl2 = *(const bf16x8*)&sBlo[boff + 256];
        bf16x8 bh3 = *(const bf16x8*)&sBhi[boff + 384];
        bf16x8 bl3 = *(const bf16x8*)&sBlo[boff + 384];
        acc0 = MFMA(ahi, bh0, acc0); acc0 = MFMA(ahi, bl0, acc0); acc0 = MFMA(alo, bh0, acc0);
        acc1 = MFMA(ahi, bh1, acc1); acc1 = MFMA(ahi, bl1, acc1); acc1 = MFMA(alo, bh1, acc1);
        acc2 = MFMA(ahi, bh2, acc2); acc2 = MFMA(ahi, bl2, acc2); acc2 = MFMA(alo, bh2, acc2);
        acc3 = MFMA(ahi, bh3, acc3); acc3 = MFMA(ahi, bl3, acc3); acc3 = MFMA(alo, bh3, acc3);
        __syncthreads();
    }
    // C/D layout (m89-verified): col = lane&15, row = (lane>>4)*4 + q
    const int orow = brow + wr * 16 + kg * 4;
    const int ocol = bcol + fr;
#pragma unroll
    for (int q = 0; q < 4; ++q) {
        H[(size_t)(orow + q) * OUTF + ocol + 0]  = acc0[q];
        H[(size_t)(orow + q) * OUTF + ocol + 16] = acc1[q];
        H[(size_t)(orow + q) * OUTF + ocol + 32] = acc2[q];
        H[(size_t)(orow + q) * OUTF + ocol + 48] = acc3[q];
    }
}

// ---------------- Kernel 2: src = H @ a[:F], dst = H @ a[F:] ----------------
__global__ __launch_bounds__(256) void k_srcdst(const float* __restrict__ H,
                                                const float* __restrict__ a,
                                                float* __restrict__ src,
                                                float* __restrict__ dst) {
    const int wv = threadIdx.x >> 6;
    const int ln = threadIdx.x & 63;
    const int row = blockIdx.x * 4 + wv;
    float4 hv = *(const float4*)(H + (size_t)row * OUTF + ln * 4);
    float4 a1 = *(const float4*)(a + ln * 4);
    float4 a2 = *(const float4*)(a + OUTF + ln * 4);
    float s = hv.x * a1.x + hv.y * a1.y + hv.z * a1.z + hv.w * a1.w;
    float d = hv.x * a2.x + hv.y * a2.y + hv.z * a2.z + hv.w * a2.w;
#pragma unroll
    for (int o = 32; o > 0; o >>= 1) {
        s += __shfl_down(s, o);
        d += __shfl_down(d, o);
    }
    if (ln == 0) { src[row] = s; dst[row] = d; }
}

// ---------------- Kernel 3: rank-by-counting "sort" ----------------
__global__ __launch_bounds__(256) void k_rank(const float* __restrict__ dstv,
                                              float* __restrict__ dsts,
                                              int* __restrict__ perm) {
    __shared__ float key[NR];
    const int tid = threadIdx.x;
#pragma unroll
    for (int i = 0; i < 8; ++i)
        *(float4*)(key + 4 * (tid + 256 * i)) = *(const float4*)(dstv + 4 * (tid + 256 * i));
    __syncthreads();
    const int el = blockIdx.x * 32 + (tid >> 3);
    const int sub = tid & 7;
    const float my = key[el];
    const int sbase = sub << 10;
    int cnt = 0;
#pragma unroll 4
    for (int i = 0; i < 256; ++i) {
        const int off = ((i + sub) << 2) & 1023;
        const int k0 = sbase + off;
        float4 v = *(const float4*)(key + k0);
        cnt += (int)((v.x < my) | ((v.x == my) & (k0 + 0 < el)));
        cnt += (int)((v.y < my) | ((v.y == my) & (k0 + 1 < el)));
        cnt += (int)((v.z < my) | ((v.z == my) & (k0 + 2 < el)));
        cnt += (int)((v.w < my) | ((v.w == my) & (k0 + 3 < el)));
    }
    cnt += __shfl_down(cnt, 4);
    cnt += __shfl_down(cnt, 2);
    cnt += __shfl_down(cnt, 1);
    if (sub == 0) {
        dsts[cnt] = my;
        perm[cnt] = el;
    }
}

// ---------------- Kernel 4: weights + scalar prefix scans (1 block) ----------------
__global__ __launch_bounds__(1024) void k_scan(const float* __restrict__ dsts,
                                               float* __restrict__ wplus,
                                               float* __restrict__ wminus,
                                               float* __restrict__ Splus,
                                               float* __restrict__ Sminus) {
    __shared__ float wsP[16], wsM[16];
    const int t = threadIdx.x;
    const int lane = t & 63;
    const float D = dsts[NR - 1];
    float4 v0 = *(const float4*)(dsts + t * 8);
    float4 v1 = *(const float4*)(dsts + t * 8 + 4);
    float vv[8] = {v0.x, v0.y, v0.z, v0.w, v1.x, v1.y, v1.z, v1.w};
    float wp[8], wm[8];
    float sp = 0.f, sm = 0.f;
#pragma unroll
    for (int j = 0; j < 8; ++j) {
        wp[j] = expf(vv[j] - D);
        wm[j] = expf(ALPHA * vv[j]);
        sp += wp[j]; sm += wm[j];
    }
    *(float4*)(wplus + t * 8)      = make_float4(wp[0], wp[1], wp[2], wp[3]);
    *(float4*)(wplus + t * 8 + 4)  = make_float4(wp[4], wp[5], wp[6], wp[7]);
    *(float4*)(wminus + t * 8)     = make_float4(wm[0], wm[1], wm[2], wm[3]);
    *(float4*)(wminus + t * 8 + 4) = make_float4(wm[4], wm[5], wm[6], wm[7]);
    float ip = sp, im = sm;
#pragma unroll
    for (int o = 1; o < 64; o <<= 1) {
        float tp = __shfl_up(ip, o);
        float tm = __shfl_up(im, o);
        if (lane >= o) { ip += tp; im += tm; }
    }
    if (lane == 63) { wsP[t >> 6] = ip; wsM[t >> 6] = im; }
    __syncthreads();
    if (t < 16) {
        float a = wsP[t], b = wsM[t];
#pragma unroll
        for (int o = 1; o < 16; o <<= 1) {
            float ta = __shfl_up(a, o);
            float tb = __shfl_up(b, o);
            if (t >= o) { a += ta; b += tb; }
        }
        wsP[t] = a; wsM[t] = b;
    }
    __syncthreads();
    const int w = t >> 6;
    float rp = (w ? wsP[w - 1] : 0.f) + (ip - sp);
    float rm = (w ? wsM[w - 1] : 0.f) + (im - sm);
#pragma unroll
    for (int j = 0; j < 8; ++j) {
        rp += wp[j]; rm += wm[j];
        Splus[t * 8 + j + 1] = rp;
        Sminus[t * 8 + j + 1] = rm;
    }
    if (t == 0) { Splus[0] = 0.f; Sminus[0] = 0.f; }
}

// ---------------- Kernel 5: per-chunk (32-row) weighted sums ----------------
// 512 blocks x 128 thr (2/CU); perm/w preloaded to LDS; 8 H-row loads in flight.
__global__ __launch_bounds__(128) void k_chunksum(const float* __restrict__ H,
                                                  const int* __restrict__ perm,
                                                  const float* __restrict__ wplus,
                                                  const float* __restrict__ wminus,
                                                  float* __restrict__ chunkP,
                                                  float* __restrict__ chunkM) {
    __shared__ int sp[32];
    __shared__ float swp[32], swm[32];
    const int b = blockIdx.x >> 1;
    const int f = (blockIdx.x & 1) * 128 + threadIdx.x;
    if (threadIdx.x < 32) {
        int g = b * 32 + threadIdx.x;
        sp[threadIdx.x] = perm[g];
        swp[threadIdx.x] = wplus[g];
        swm[threadIdx.x] = wminus[g];
    }
    __syncthreads();
    float aP = 0.f, aM = 0.f;
    for (int k0 = 0; k0 < 32; k0 += 8) {
        float hv[8];
#pragma unroll
        for (int j = 0; j < 8; ++j) hv[j] = H[(size_t)sp[k0 + j] * OUTF + f];
#pragma unroll
        for (int j = 0; j < 8; ++j) {
            aP = fmaf(swp[k0 + j], hv[j], aP);
            aM = fmaf(swm[k0 + j], hv[j], aM);
        }
    }
    chunkP[b * OUTF + f] = aP;
    chunkM[b * OUTF + f] = aM;
}

// ---------------- Kernel 6: scan chunk sums per column ----------------
__global__ __launch_bounds__(64) void k_chunkscan(const float* __restrict__ chunkP,
                                                  const float* __restrict__ chunkM,
                                                  float* __restrict__ offP,
                                                  float* __restrict__ offM,
                                                  float* __restrict__ PrefP,
                                                  float* __restrict__ PrefM) {
    const int f = blockIdx.x;
    const bool minus = (blockIdx.y != 0);
    const float* sv = minus ? chunkM : chunkP;
    float* dv = minus ? offM : offP;
    float* tot = minus ? PrefM : PrefP;
    const int l = threadIdx.x;
    float v0 = sv[(4 * l + 0) * OUTF + f];
    float v1 = sv[(4 * l + 1) * OUTF + f];
    float v2 = sv[(4 * l + 2) * OUTF + f];
    float v3 = sv[(4 * l + 3) * OUTF + f];
    float s = v0 + v1 + v2 + v3;
    float incl = s;
#pragma unroll
    for (int o = 1; o < 64; o <<= 1) {
        float t = __shfl_up(incl, o);
        if (l >= o) incl += t;
    }
    float excl = incl - s;
    dv[(4 * l + 0) * OUTF + f] = excl;
    dv[(4 * l + 1) * OUTF + f] = excl + v0;
    dv[(4 * l + 2) * OUTF + f] = excl + v0 + v1;
    dv[(4 * l + 3) * OUTF + f] = excl + v0 + v1 + v2;
    if (l == 63) tot[(size_t)NR * OUTF + f] = incl;  // grand total row [8192]
}

// ---------------- Kernel 7: write full [8193][256] prefix arrays ----------------
__global__ __launch_bounds__(128) void k_writepref(const float* __restrict__ H,
                                                   const int* __restrict__ perm,
                                                   const float* __restrict__ wplus,
                                                   const float* __restrict__ wminus,
                                                   const float* __restrict__ offP,
                                                   const float* __restrict__ offM,
                                                   float* __restrict__ PrefP,
                                                   float* __restrict__ PrefM) {
    __shared__ int sp[32];
    __shared__ float swp[32], swm[32];
    const int b = blockIdx.x >> 1;
    const int f = (blockIdx.x & 1) * 128 + threadIdx.x;
    if (threadIdx.x < 32) {
        int g = b * 32 + threadIdx.x;
        sp[threadIdx.x] = perm[g];
        swp[threadIdx.x] = wplus[g];
        swm[threadIdx.x] = wminus[g];
    }
    __syncthreads();
    float aP = offP[b * OUTF + f];
    float aM = offM[b * OUTF + f];
    for (int k0 = 0; k0 < 32; k0 += 8) {
        float hv[8];
#pragma unroll
        for (int j = 0; j < 8; ++j) hv[j] = H[(size_t)sp[k0 + j] * OUTF + f];
#pragma unroll
        for (int j = 0; j < 8; ++j) {
            int g = b * 32 + k0 + j;
            PrefP[(size_t)g * OUTF + f] = aP;
            PrefM[(size_t)g * OUTF + f] = aM;
            aP = fmaf(swp[k0 + j], hv[j], aP);
            aM = fmaf(swm[k0 + j], hv[j], aM);
        }
    }
}

// ---------------- Kernel 8: per-row combine + ELU ----------------
__global__ __launch_bounds__(256) void k_out(const float* __restrict__ src,
                                             const float* __restrict__ dsts,
                                             const float* __restrict__ Splus,
                                             const float* __restrict__ Sminus,
                                             const float* __restrict__ PrefP,
                                             const float* __restrict__ PrefM,
                                             float* __restrict__ out) {
    const int i = blockIdx.x, f = threadIdx.x;
    const float si = src[i];
    const float D = dsts[NR - 1];
    const float thr = -si;
    int lo = 0, hi = NR;
    while (lo < hi) {
        int mid = (lo + hi) >> 1;
        if (dsts[mid] <= thr) lo = mid + 1; else hi = mid;
    }
    const int t = lo;
    const float cP = expf(si + D);
    const float cM = expf(ALPHA * si);
    const float SP = Splus[NR] - Splus[t];
    const float SM = Sminus[t];
    const float inv = 1.f / (cP * SP + cM * SM);
    const float pP = PrefP[(size_t)NR * OUTF + f] - PrefP[(size_t)t * OUTF + f];
    const float pM = PrefM[(size_t)t * OUTF + f];
    const float v = (cP * pP + cM * pM) * inv;
    out[(size_t)i * OUTF + f] = v > 0.f ? v : expm1f(v);
}

extern "C" void kernel_launch(void* const* d_in, const int* in_sizes, int n_in,
                              void* d_out, int out_size, void* d_ws, size_t ws_size,
                              hipStream_t stream) {
    const float* X = (const float*)d_in[0];
    // d_in[1] = adj (unused by reference forward)
    const float* W = (const float*)d_in[2];
    const float* a = (const float*)d_in[3];
    float* out = (float*)d_out;

    char* ws = (char*)d_ws;
    size_t off = 0;
    auto carve = [&](size_t bytes) -> void* {
        void* p = ws + off;
        off += (bytes + 1023) & ~(size_t)1023;
        return p;
    };
    float*  H      = (float*)carve((size_t)NR * OUTF * 4);
    ushort* Xhi    = (ushort*)carve((size_t)NR * INF_ * 2);
    ushort* Xlo    = (ushort*)carve((size_t)NR * INF_ * 2);
    ushort* Wthi   = (ushort*)carve((size_t)OUTF * INF_ * 2);
    ushort* Wtlo   = (ushort*)carve((size_t)OUTF * INF_ * 2);
    float*  src    = (float*)carve(NR * 4);
    float*  dstv   = (float*)carve(NR * 4);
    float*  dsts   = (float*)carve(NR * 4);
    int*    perm   = (int*)carve(NR * 4);
    float*  wplus  = (float*)carve(NR * 4);
    float*  wminus = (float*)carve(NR * 4);
    float*  Splus  = (float*)carve((NR + 1) * 4);
    float*  Sminus = (float*)carve((NR + 1) * 4);
    float*  chunkP = (float*)carve(256 * OUTF * 4);
    float*  chunkM = (float*)carve(256 * OUTF * 4);
    float*  offP   = (float*)carve(256 * OUTF * 4);
    float*  offM   = (float*)carve(256 * OUTF * 4);
    float*  PrefP  = (float*)carve((size_t)(NR + 1) * OUTF * 4);
    float*  PrefM  = (float*)carve((size_t)(NR + 1) * OUTF * 4);

    k_convX<<<NR * INF_ / (256 * 8), 256, 0, stream>>>(X, Xhi, Xlo);
    k_convWT<<<OUTF, 128, 0, stream>>>(W, Wthi, Wtlo);
    k_gemm<<<dim3(NR / 64, OUTF / 64), 256, 0, stream>>>(Xhi, Xlo, Wthi, Wtlo, H);
    k_srcdst<<<NR / 4, 256, 0, stream>>>(H, a, src, dstv);
    k_rank<<<NR / 32, 256, 0, stream>>>(dstv, dsts, perm);
    k_scan<<<1, 1024, 0, stream>>>(dsts, wplus, wminus, Splus, Sminus);
    k_chunksum<<<512, 128, 0, stream>>>(H, perm, wplus, wminus, chunkP, chunkM);
    k_chunkscan<<<dim3(OUTF, 2), 64, 0, stream>>>(chunkP, chunkM, offP, offM, PrefP, PrefM);
    k_writepref<<<512, 128, 0, stream>>>(H, perm, wplus, wminus, offP, offM, PrefP, PrefM);
    k_out<<<NR, 256, 0, stream>>>(src, dsts, Splus, Sminus, PrefP, PrefM, out);
}